// Round 7
// baseline (4601.900 us; speedup 1.0000x reference)
//
#include <hip/hip_runtime.h>
#include <hip/hip_bf16.h>

#define HC 252
#define WC 252
#define CD 256
#define NHEADS 16

// XP padded image: [b][ci][h 0..251][wp 0..263], wp = w_img + 4
#define XP_W 264
#define XP_HW (252*264)
#define XP_CHW (256*252*264)

typedef unsigned short u16;
typedef unsigned int u32;
typedef __attribute__((ext_vector_type(8))) short bf16x8;
typedef __attribute__((ext_vector_type(4))) float f32x4;
typedef __attribute__((ext_vector_type(4))) u32 u32x4;
typedef __attribute__((ext_vector_type(2))) u32 u32x2;

// ---- workspace layout (bytes) ----
#define XP_BYTES (2u * (unsigned)XP_CHW * 2u)      // 68,124,672
#define ZP_OFF   XP_BYTES
#define ZP_BYTES 409600u
#define WT_OFF   (ZP_OFF + ZP_BYTES)
#define WT_ELEMS (128*8192)                        // 1,048,576 bf16 [s][kb][co][8]
#define WPW_OFF  (WT_OFF + (unsigned)WT_ELEMS*2u)
#define WPW_ELEMS (8*8192)                         // 65,536 bf16
#define WQ_OFF   (WPW_OFF + (unsigned)WPW_ELEMS*2u)
#define WQ_ELEMS (768*256)                         // 196,608 bf16
#define BIAS_OFF (WQ_OFF + (unsigned)WQ_ELEMS*2u)

__device__ __forceinline__ u16 bfu(float f) {
    __hip_bfloat16 h = __float2bfloat16(f);
    return *(reinterpret_cast<u16*>(&h));
}
__device__ __forceinline__ u32 pack2(float a, float b) {
    return (u32)bfu(a) | ((u32)bfu(b) << 16);
}

// ---------------- Kernel A: fused qkv + window attention (MFMA) --------------
// grid 2048 (XCD-swizzled), 256 threads (4 waves, 4 heads/wave, sequential).
__global__ __launch_bounds__(256, 2) void attn_mfma(
    const float* __restrict__ x, const u16* __restrict__ WQ,
    const float* __restrict__ BIASF, u16* __restrict__ xp)
{
    __shared__ __align__(16) char smem[73728];

    const int bid = blockIdx.x;
    const int zz = (bid & 7) * 256 + (bid >> 3);   // XCD-bijective swizzle
    const int wx = zz & 31, wy = (zz >> 5) & 31, b = zz >> 10;
    const int tid = threadIdx.x;
    const int lane = tid & 63, wid = tid >> 6;
    const int g = lane >> 4, li = lane & 15;

    // ---- stage Xwin (fp32 x -> bf16 LDS, transposed, reflect-padded) ----
    {
        int ci = tid;
        const float* srcc = x + (size_t)(b * 256 + ci) * (HC * WC);
        #pragma unroll
        for (int r = 0; r < 8; ++r) {
            int h = wy * 8 + r; if (h >= HC) h = 2 * HC - 2 - h;
            const float* src = srcc + h * WC;
            float v[8];
            if (wx == 31) {
                #pragma unroll
                for (int c = 0; c < 8; ++c) {
                    int w = 248 + c; if (w >= WC) w = 2 * WC - 2 - w;
                    v[c] = src[w];
                }
            } else {
                float4 f0 = *(const float4*)(src + wx * 8);
                float4 f1 = *(const float4*)(src + wx * 8 + 4);
                v[0]=f0.x; v[1]=f0.y; v[2]=f0.z; v[3]=f0.w;
                v[4]=f1.x; v[5]=f1.y; v[6]=f1.z; v[7]=f1.w;
            }
            #pragma unroll
            for (int c = 0; c < 8; ++c) {
                int pos = r * 8 + c;
                int byte = pos * 512 + ((ci * 2) ^ ((pos & 7) << 4));
                *(u16*)(smem + byte) = bfu(v[c]);
            }
        }
    }
    __syncthreads();

    const int WB = 32768 + wid * 10240;
    char* Qb = smem + WB;
    char* Kb = smem + WB + 2048;
    char* Vb = smem + WB + 4096;
    char* Pb = smem + WB + 6144;

    const bf16x8 zf = {0,0,0,0,0,0,0,0};

    #pragma unroll 1
    for (int hh = 0; hh < 4; ++hh) {
        const int head = wid * 4 + hh;

        f32x4 acc[3][4];
        #pragma unroll
        for (int p = 0; p < 3; ++p)
            #pragma unroll
            for (int nf = 0; nf < 4; ++nf) acc[p][nf] = (f32x4){0.f,0.f,0.f,0.f};

        for (int ks = 0; ks < 8; ++ks) {
            bf16x8 bx[4];
            #pragma unroll
            for (int nf = 0; nf < 4; ++nf) {
                int pos = 16 * nf + li;
                int byte = pos * 512 + ((ks * 64 + 16 * g) ^ ((pos & 7) << 4));
                bx[nf] = *(const bf16x8*)(smem + byte);
            }
            bf16x8 aw[3];
            #pragma unroll
            for (int p = 0; p < 3; ++p) {
                int o = p * 256 + head * 16 + li;
                aw[p] = *(const bf16x8*)(WQ + o * 256 + ks * 32 + 8 * g);
            }
            __builtin_amdgcn_s_setprio(1);
            #pragma unroll
            for (int p = 0; p < 3; ++p)
                #pragma unroll
                for (int nf = 0; nf < 4; ++nf)
                    acc[p][nf] = __builtin_amdgcn_mfma_f32_16x16x32_bf16(aw[p], bx[nf], acc[p][nf], 0, 0, 0);
            __builtin_amdgcn_s_setprio(0);
        }

        #pragma unroll
        for (int p = 0; p < 3; ++p) {
            if (p < 2) {
                char* base = (p == 0) ? Qb : Kb;
                #pragma unroll
                for (int nf = 0; nf < 4; ++nf) {
                    int pos = 16 * nf + li;
                    u32 lo = pack2(acc[p][nf][0], acc[p][nf][1]);
                    u32 hi = pack2(acc[p][nf][2], acc[p][nf][3]);
                    int byte = pos * 32 + ((8 * g) ^ (((pos >> 2) & 1) << 4));
                    *(u32x2*)(base + byte) = (u32x2){lo, hi};
                }
            } else {
                #pragma unroll
                for (int nf = 0; nf < 4; ++nf) {
                    int pos = 16 * nf + li;
                    #pragma unroll
                    for (int r = 0; r < 4; ++r) {
                        int d = 4 * g + r;
                        int byte = (pos >> 3) * 256 + d * 16 + (pos & 7) * 2;
                        *(u16*)(Vb + byte) = bfu(acc[p][nf][r]);
                    }
                }
            }
        }

        f32x4 s[4][4];
        #pragma unroll
        for (int mf = 0; mf < 4; ++mf)
            #pragma unroll
            for (int nf = 0; nf < 4; ++nf) s[mf][nf] = (f32x4){0.f,0.f,0.f,0.f};
        bf16x8 bk[4];
        #pragma unroll
        for (int nf = 0; nf < 4; ++nf) {
            int pos = 16 * nf + li;
            bk[nf] = (g < 2) ? *(const bf16x8*)(Kb + pos * 32 + ((16 * g) ^ (((pos >> 2) & 1) << 4))) : zf;
        }
        __builtin_amdgcn_s_setprio(1);
        #pragma unroll
        for (int mf = 0; mf < 4; ++mf) {
            int pos = 16 * mf + li;
            bf16x8 aq = (g < 2) ? *(const bf16x8*)(Qb + pos * 32 + ((16 * g) ^ (((pos >> 2) & 1) << 4))) : zf;
            #pragma unroll
            for (int nf = 0; nf < 4; ++nf)
                s[mf][nf] = __builtin_amdgcn_mfma_f32_16x16x32_bf16(aq, bk[nf], s[mf][nf], 0, 0, 0);
        }
        __builtin_amdgcn_s_setprio(0);

        f32x4 e[4][4];
        f32x4 rs[4];
        #pragma unroll
        for (int mf = 0; mf < 4; ++mf) rs[mf] = (f32x4){0.f,0.f,0.f,0.f};
        #pragma unroll
        for (int mf = 0; mf < 4; ++mf)
            #pragma unroll
            for (int nf = 0; nf < 4; ++nf) {
                f32x4 b4 = *(const f32x4*)(BIASF + (((head * 4 + mf) * 4 + nf) * 64 + lane) * 4);
                #pragma unroll
                for (int r = 0; r < 4; ++r) {
                    float ev = __expf(s[mf][nf][r] * 0.25f + b4[r]);
                    e[mf][nf][r] = ev;
                    rs[mf][r] += ev;
                }
            }
        #pragma unroll
        for (int mf = 0; mf < 4; ++mf)
            #pragma unroll
            for (int r = 0; r < 4; ++r) {
                float t = rs[mf][r];
                t += __shfl_xor(t, 1); t += __shfl_xor(t, 2);
                t += __shfl_xor(t, 4); t += __shfl_xor(t, 8);
                rs[mf][r] = t;
            }

        f32x4 o[4];
        #pragma unroll
        for (int mf = 0; mf < 4; ++mf) o[mf] = (f32x4){0.f,0.f,0.f,0.f};
        const bool even = !(lane & 1);
        #pragma unroll
        for (int hf = 0; hf < 2; ++hf) {
            #pragma unroll
            for (int mf = 0; mf < 4; ++mf)
                #pragma unroll
                for (int nfl = 0; nfl < 2; ++nfl) {
                    f32x4 ee = e[mf][2 * hf + nfl];
                    float p0 = __shfl_xor(ee[0], 1), p1 = __shfl_xor(ee[1], 1);
                    float p2 = __shfl_xor(ee[2], 1), p3 = __shfl_xor(ee[3], 1);
                    int jl = 16 * nfl + (li & ~1);
                    u32 w0, w1; int r0;
                    if (even) { w0 = pack2(ee[0], p0); w1 = pack2(ee[1], p1); r0 = 0; }
                    else      { w0 = pack2(p2, ee[2]); w1 = pack2(p3, ee[3]); r0 = 2; }
                    int i0 = 16 * mf + 4 * g + r0, i1 = i0 + 1;
                    *(u32*)(Pb + i0 * 64 + ((2 * jl) ^ ((i0 & 3) << 4))) = w0;
                    *(u32*)(Pb + i1 * 64 + ((2 * jl) ^ ((i1 & 3) << 4))) = w1;
                }
            bf16x8 bv = *(const bf16x8*)(Vb + (4 * hf + g) * 256 + li * 16);
            __builtin_amdgcn_s_setprio(1);
            #pragma unroll
            for (int mf = 0; mf < 4; ++mf) {
                int i = 16 * mf + li;
                bf16x8 ap = *(const bf16x8*)(Pb + i * 64 + ((16 * g) ^ ((i & 3) << 4)));
                o[mf] = __builtin_amdgcn_mfma_f32_16x16x32_bf16(ap, bv, o[mf], 0, 0, 0);
            }
            __builtin_amdgcn_s_setprio(0);
        }

        #pragma unroll
        for (int mf = 0; mf < 4; ++mf) {
            int h = wy * 8 + 2 * mf + (g >> 1);
            int wbase = wx * 8 + 4 * (g & 1);
            if (h < HC && wbase < WC) {
                float v0 = o[mf][0] / rs[mf][0], v1 = o[mf][1] / rs[mf][1];
                float v2 = o[mf][2] / rs[mf][2], v3 = o[mf][3] / rs[mf][3];
                size_t idx = ((size_t)(b * 256 + head * 16 + li) * HC + h) * XP_W + wbase + 4;
                *(u32x2*)(xp + idx) = (u32x2){pack2(v0, v1), pack2(v2, v3)};
            }
        }
    }
}

// ---------------- weight prep: WT2, WP2, ZP, WQ(bf16), BIASF -----------------
__global__ __launch_bounds__(256) void wprep_kernel(
    const float* __restrict__ wh, const float* __restrict__ wv,
    const float* __restrict__ wpw, const float* __restrict__ wqkv,
    const float* __restrict__ btab, u16* __restrict__ wsu)
{
    int i = blockIdx.x * 256 + threadIdx.x;
    u16* WT = wsu + WT_OFF / 2;
    u16* WP = wsu + WPW_OFF / 2;
    u16* ZP = wsu + ZP_OFF / 2;
    u16* WQp = wsu + WQ_OFF / 2;
    float* BF = (float*)(wsu + BIAS_OFF / 2);
    if (i < WT_ELEMS) {
        int j = i & 7, co = (i >> 3) & 255, kb = (i >> 11) & 3, s = i >> 13;
        float v = (s < 64) ? wh[co * 2048 + s * 32 + kb * 8 + j]
                           : wv[co * 2048 + (s - 64) * 32 + kb * 8 + j];
        WT[i] = bfu(v);
    } else if (i < WT_ELEMS + WPW_ELEMS) {
        int i2 = i - WT_ELEMS;
        int j = i2 & 7, co = (i2 >> 3) & 255, kb = (i2 >> 11) & 3, s = i2 >> 13;
        WP[i2] = bfu(wpw[co * 256 + s * 32 + kb * 8 + j]);
    } else if (i < WT_ELEMS + WPW_ELEMS + (int)(ZP_BYTES / 2)) {
        ZP[i - WT_ELEMS - WPW_ELEMS] = 0;
    } else if (i < WT_ELEMS + WPW_ELEMS + (int)(ZP_BYTES / 2) + WQ_ELEMS) {
        int i4 = i - WT_ELEMS - WPW_ELEMS - (int)(ZP_BYTES / 2);
        WQp[i4] = bfu(wqkv[i4]);
    } else {
        int i5 = i - WT_ELEMS - WPW_ELEMS - (int)(ZP_BYTES / 2) - WQ_ELEMS;
        if (i5 < 16384) {
            int lane = i5 & 63, nf = (i5 >> 6) & 3, mf = (i5 >> 8) & 3, head = i5 >> 10;
            int gg = lane >> 4, ll = lane & 15;
            #pragma unroll
            for (int r = 0; r < 4; ++r) {
                int row = 16 * mf + 4 * gg + r;
                int col = 16 * nf + ll;
                int dy = (row >> 3) - (col >> 3) + 7;
                int dx = (row & 7) - (col & 7) + 7;
                BF[i5 * 4 + r] = btab[(dy * 15 + dx) * NHEADS + head];
            }
        }
    }
}

// ---------------- halo fill for XP: wp 0..3, 256..263 ------------------------
__global__ __launch_bounds__(256) void halo_kernel(u16* __restrict__ xp)
{
    int i = blockIdx.x * 256 + threadIdx.x;
    if (i >= 129024 * 12) return;
    int row = i / 12, c = i % 12;
    int wp = (c < 4) ? c : 252 + c;
    u16 v = 0;
    if (wp == 256) v = xp[row * XP_W + 254];
    xp[row * XP_W + wp] = v;
}

// ---------------- Kernel B: sepconv bf16 MFMA, K=4096, 2-deep pipeline -------
// grid 504 = (b,h), XCD-swizzled. 512 thr, 8 waves of 128co x 64w.
__global__ __launch_bounds__(512, 4) void sepconv_mfma(
    const u16* __restrict__ xp, const u16* __restrict__ WT,
    const u16* __restrict__ ZP,
    const float* __restrict__ b_h, const float* __restrict__ b_v,
    float* __restrict__ P)
{
    __shared__ u16 As[2][8192];       // [kb][co^swz][8]
    __shared__ u16 Bs[2][256 * 36];   // [w][kk], rows padded to 36 u16

    const int bid = blockIdx.x;
    const int zz = (bid & 7) * 63 + (bid >> 3);
    const int h = zz % HC, b = zz / HC;
    const int tid = threadIdx.x;
    const int lane = tid & 63, wid = tid >> 6;
    const int wr = wid >> 2, wc = wid & 3;
    const int cq = lane & 15, kb = lane >> 4;

    const int wl2 = (tid & 127) * 2;
    const int oc = tid >> 7;

    const u16* hcur[8];
    int hstep[8];
    #pragma unroll
    for (int t = 0; t < 8; ++t) {
        int j = h + t - 3;
        bool valid = (j >= 0 && j <= 252);
        int jr = (j == 252) ? 250 : j;
        hcur[t] = valid ? (xp + (size_t)b * XP_CHW + (size_t)jr * XP_W) : ZP;
        hstep[t] = valid ? 4 * XP_HW : 0;
    }
    const u16* vbase = xp + (size_t)b * XP_CHW + (size_t)h * XP_W;
    const int hvoff = oc * XP_HW + wl2 + 4;

    const int bw0 = wl2 * 36 + oc * 8;
    const int bw1 = bw0 + 36;

    f32x4 acc[8][4];
    #pragma unroll
    for (int m = 0; m < 8; ++m)
        #pragma unroll
        for (int n = 0; n < 4; ++n) acc[m][n] = (f32x4){0.f, 0.f, 0.f, 0.f};

    int aw0, aw1;
    {
        int c0 = tid, c1 = 512 + tid;
        aw0 = ((c0 >> 8) * 256 + ((c0 & 255) ^ (((c0 >> 8) & 3) << 1))) * 8;
        aw1 = ((c1 >> 8) * 256 + ((c1 & 255) ^ (((c1 >> 8) & 3) << 1))) * 8;
    }

    u32x4 hA[2]; u32 hB[8];   // staging set written next
    u32x4 rA[2]; u32 rB[8];   // staging set being loaded

#define SC_LOADA(t, RA)                                                        \
    RA[0] = *(const u32x4*)(WT + (size_t)(t) * 8192 + (size_t)tid * 8);        \
    RA[1] = *(const u32x4*)(WT + (size_t)(t) * 8192 + (size_t)(512 + tid) * 8);

#define SC_ADV()                                                               \
    { _Pragma("unroll") for (int tt = 0; tt < 8; ++tt) hcur[tt] += hstep[tt]; }

#define SC_LOADB_H(RB)                                                         \
    { _Pragma("unroll") for (int tt = 0; tt < 8; ++tt)                         \
          RB[tt] = *(const u32*)(hcur[tt] + hvoff); }

#define SC_LOAD(t, RA, RB)                                                     \
    if ((t) < 128) {                                                           \
        SC_LOADA(t, RA)                                                        \
        if ((t) < 64) {                                                        \
            SC_ADV()                                                           \
            SC_LOADB_H(RB)                                                     \
        } else {                                                               \
            int off_ = (((t) - 64) * 4 + oc) * XP_HW + wl2;                    \
            _Pragma("unroll") for (int l = 0; l < 6; ++l)                      \
                RB[l] = *(const u32*)(vbase + off_ + 2 * l);                   \
        }                                                                      \
    }

#define SC_WRITE(t, buf, RA, RB)                                               \
    if ((t) < 128) {                                                           \
        *(u32x4*)&As[buf][aw0] = RA[0];                                        \
        *(u32x4*)&As[buf][aw1] = RA[1];                                        \
        union { bf16x8 v; u32 u[4]; } p0_, p1_;                                \
        if ((t) < 64) {                                                        \
            _Pragma("unroll") for (int q = 0; q < 4; ++q) {                    \
                p0_.u[q] = __builtin_amdgcn_perm(RB[2*q+1], RB[2*q], 0x05040100u); \
                p1_.u[q] = __builtin_amdgcn_perm(RB[2*q+1], RB[2*q], 0x07060302u); \
            }                                                                  \
        } else {                                                               \
            _Pragma("unroll") for (int q = 0; q < 4; ++q)                      \
                p0_.u[q] = __builtin_amdgcn_alignbit(RB[q+1], RB[q], 16);      \
            p1_.u[0] = RB[1]; p1_.u[1] = RB[2]; p1_.u[2] = RB[3]; p1_.u[3] = RB[4]; \
        }                                                                      \
        *(bf16x8*)&Bs[buf][bw0] = p0_.v;                                       \
        *(bf16x8*)&Bs[buf][bw1] = p1_.v;                                       \
    }

#define SC_COMPUTE(buf)                                                        \
    {                                                                          \
        bf16x8 af[8], bfr[4];                                                  \
        _Pragma("unroll") for (int m = 0; m < 8; ++m) {                        \
            int row_ = wr * 128 + m * 16 + cq;                                 \
            af[m] = *(const bf16x8*)&As[buf][(kb * 256 + (row_ ^ (kb << 1))) * 8]; \
        }                                                                      \
        _Pragma("unroll") for (int n = 0; n < 4; ++n)                          \
            bfr[n] = *(const bf16x8*)&Bs[buf][(wc * 64 + n * 16 + cq) * 36 + kb * 8]; \
        __builtin_amdgcn_s_setprio(1);                                         \
        _Pragma("unroll") for (int m = 0; m < 8; ++m) {                        \
            _Pragma("unroll") for (int n = 0; n < 4; ++n)                      \
                acc[m][n] = __builtin_amdgcn_mfma_f32_16x16x32_bf16(af[m], bfr[n], acc[m][n], 0, 0, 0); \
        }                                                                      \
        __builtin_amdgcn_s_setprio(0);                                         \
    }

    // ---- prologue: t=0 -> LDS[0]; t=1 held in hA/hB ----
    SC_LOADA(0, hA)
    SC_LOADB_H(hB)
    SC_WRITE(0, 0, hA, hB)
    SC_ADV()
    SC_LOADA(1, hA)
    SC_LOADB_H(hB)

    #pragma unroll 1
    for (int sb = 0; sb < 128; sb += 2) {
        __syncthreads();
        SC_LOAD(sb + 2, rA, rB)           // loads for s+2 in flight across barrier
        SC_COMPUTE(0)
        SC_WRITE(sb + 1, 1, hA, hB)       // write set loaded a full step ago
        __syncthreads();
        SC_LOAD(sb + 3, hA, hB)
        SC_COMPUTE(1)
        SC_WRITE(sb + 2, 0, rA, rB)
    }

#undef SC_LOADA
#undef SC_ADV
#undef SC_LOADB_H
#undef SC_LOAD
#undef SC_WRITE
#undef SC_COMPUTE

    // ---- epilogue: bias + fp32 store ----
    const int rq = lane >> 4, cc = lane & 15;
    #pragma unroll
    for (int m = 0; m < 8; ++m) {
        int cgb = wr * 128 + m * 16 + rq * 4;
        float bias[4];
        #pragma unroll
        for (int rr = 0; rr < 4; ++rr) bias[rr] = b_h[cgb + rr] + b_v[cgb + rr];
        #pragma unroll
        for (int n = 0; n < 4; ++n) {
            int wg = wc * 64 + n * 16 + cc;
            if (wg < WC) {
                #pragma unroll
                for (int rr = 0; rr < 4; ++rr)
                    P[((size_t)(b * CD + cgb + rr) * HC + h) * WC + wg] = acc[m][n][rr] + bias[rr];
            }
        }
    }
}

// ---------------- Kernel C: depthwise 8x8 conv + BN -> bf16 Y ----------------
__global__ __launch_bounds__(256) void dwbn_kernel(
    const float* __restrict__ P, const float* __restrict__ w_dw,
    const float* __restrict__ gamma, const float* __restrict__ beta,
    const float* __restrict__ mean, const float* __restrict__ var,
    __hip_bfloat16* __restrict__ Yb)
{
    __shared__ float ps[15][42];
    __shared__ float wd[64];
    const int bw = blockIdx.x, bh = blockIdx.y, bz = blockIdx.z;
    const int b = bz >> 8, c = bz & 255;
    const int h0 = bh * 8, w0 = bw * 32;
    const int tid = threadIdx.x;
    if (tid < 64) wd[tid] = w_dw[c * 64 + tid];
    for (int it = 0; it < 3; ++it) {
        int flat = tid + it * 256;
        if (flat < 630) {
            int row = flat / 42, col = flat % 42;
            int j = h0 - 3 + row, wcol = w0 - 3 + col;
            float v = 0.f;
            if (j >= 0 && j <= HC && wcol >= 0 && wcol <= WC) {
                int jr = (j == HC) ? (HC - 2) : j;
                int wr2 = (wcol == WC) ? (WC - 2) : wcol;
                v = P[((b * CD + c) * HC + jr) * WC + wr2];
            }
            ps[row][col] = v;
        }
    }
    __syncthreads();
    const int r = tid >> 5, cc = tid & 31;
    const int h = h0 + r, w = w0 + cc;
    if (h < HC && w < WC) {
        float s = 0.f;
        #pragma unroll
        for (int u = 0; u < 8; ++u)
            #pragma unroll
            for (int v2 = 0; v2 < 8; ++v2)
                s += wd[u * 8 + v2] * ps[r + u][cc + v2];
        const float inv = gamma[c] * rsqrtf(var[c] + 1e-5f);
        Yb[((b * CD + c) * HC + h) * WC + w] = __float2bfloat16(s * inv + (beta[c] - mean[c] * inv));
    }
}

// ---------------- Kernel D: pointwise 1x1, bf16 MFMA, K=256, 2-deep ----------
// grid 504 = (b,h), XCD-swizzled. 512 thr, 8 waves of 128co x 64w.
__global__ __launch_bounds__(512, 4) void pw_mfma(
    const u16* __restrict__ Y, const u16* __restrict__ WP,
    float* __restrict__ O)
{
    __shared__ u16 As[2][8192];
    __shared__ u16 Bs[2][256 * 36];

    const int bid = blockIdx.x;
    const int zz = (bid & 7) * 63 + (bid >> 3);
    const int h = zz % HC, b = zz / HC;
    const int tid = threadIdx.x;
    const int lane = tid & 63, wid = tid >> 6;
    const int wr = wid >> 2, wc = wid & 3;
    const int cq = lane & 15, kb = lane >> 4;

    const int wl2 = (tid & 127) * 2;
    const int oc = tid >> 7;

    const u16* yb = Y + ((size_t)(b * 256 + oc * 8) * HC + h) * WC + wl2;

    const int bw0 = wl2 * 36 + oc * 8;
    const int bw1 = bw0 + 36;

    f32x4 acc[8][4];
    #pragma unroll
    for (int m = 0; m < 8; ++m)
        #pragma unroll
        for (int n = 0; n < 4; ++n) acc[m][n] = (f32x4){0.f, 0.f, 0.f, 0.f};

    int aw0, aw1;
    {
        int c0 = tid, c1 = 512 + tid;
        aw0 = ((c0 >> 8) * 256 + ((c0 & 255) ^ (((c0 >> 8) & 3) << 1))) * 8;
        aw1 = ((c1 >> 8) * 256 + ((c1 & 255) ^ (((c1 >> 8) & 3) << 1))) * 8;
    }

    u32x4 hA[2]; u32 hB[8];
    u32x4 rA[2]; u32 rB[8];

#define PW_LOAD(t, RA, RB)                                                     \
    if ((t) < 8) {                                                             \
        RA[0] = *(const u32x4*)(WP + (size_t)(t) * 8192 + (size_t)tid * 8);    \
        RA[1] = *(const u32x4*)(WP + (size_t)(t) * 8192 + (size_t)(512 + tid) * 8); \
        _Pragma("unroll") for (int j = 0; j < 8; ++j)                          \
            RB[j] = *(const u32*)(yb + (size_t)((t) * 32 + j) * (HC * WC));    \
    }

#define PW_WRITE(t, buf, RA, RB)                                               \
    if ((t) < 8) {                                                             \
        *(u32x4*)&As[buf][aw0] = RA[0];                                        \
        *(u32x4*)&As[buf][aw1] = RA[1];                                        \
        union { bf16x8 v; u32 u[4]; } p0_, p1_;                                \
        _Pragma("unroll") for (int q = 0; q < 4; ++q) {                        \
            p0_.u[q] = __builtin_amdgcn_perm(RB[2*q+1], RB[2*q], 0x05040100u); \
            p1_.u[q] = __builtin_amdgcn_perm(RB[2*q+1], RB[2*q], 0x07060302u); \
        }                                                                      \
        *(bf16x8*)&Bs[buf][bw0] = p0_.v;                                       \
        *(bf16x8*)&Bs[buf][bw1] = p1_.v;                                       \
    }

#define PW_COMPUTE(buf)                                                        \
    {                                                                          \
        bf16x8 af[8], bfr[4];                                                  \
        _Pragma("unroll") for (int m = 0; m < 8; ++m) {                        \
            int row_ = wr * 128 + m * 16 + cq;                                 \
            af[m] = *(const bf16x8*)&As[buf][(kb * 256 + (row_ ^ (kb << 1))) * 8]; \
        }                                                                      \
        _Pragma("unroll") for (int n = 0; n < 4; ++n)                          \
            bfr[n] = *(const bf16x8*)&Bs[buf][(wc * 64 + n * 16 + cq) * 36 + kb * 8]; \
        __builtin_amdgcn_s_setprio(1);                                         \
        _Pragma("unroll") for (int m = 0; m < 8; ++m) {                        \
            _Pragma("unroll") for (int n = 0; n < 4; ++n)                      \
                acc[m][n] = __builtin_amdgcn_mfma_f32_16x16x32_bf16(af[m], bfr[n], acc[m][n], 0, 0, 0); \
        }                                                                      \
        __builtin_amdgcn_s_setprio(0);                                         \
    }

    // ---- prologue ----
    PW_LOAD(0, hA, hB)
    PW_WRITE(0, 0, hA, hB)
    PW_LOAD(1, hA, hB)

    #pragma unroll 1
    for (int sb = 0; sb < 8; sb += 2) {
        __syncthreads();
        PW_LOAD(sb + 2, rA, rB)
        PW_COMPUTE(0)
        PW_WRITE(sb + 1, 1, hA, hB)
        __syncthreads();
        PW_LOAD(sb + 3, hA, hB)
        PW_COMPUTE(1)
        PW_WRITE(sb + 2, 0, rA, rB)
    }

#undef PW_LOAD
#undef PW_WRITE
#undef PW_COMPUTE

    const int rq = lane >> 4, cc = lane & 15;
    #pragma unroll
    for (int m = 0; m < 8; ++m) {
        int cgb = wr * 128 + m * 16 + rq * 4;
        #pragma unroll
        for (int n = 0; n < 4; ++n) {
            int wg = wc * 64 + n * 16 + cc;
            if (wg < WC) {
                #pragma unroll
                for (int rr = 0; rr < 4; ++rr)
                    O[((size_t)(b * CD + cgb + rr) * HC + h) * WC + wg] = acc[m][n][rr];
            }
        }
    }
}

extern "C" void kernel_launch(void* const* d_in, const int* in_sizes, int n_in,
                              void* d_out, int out_size, void* d_ws, size_t ws_size,
                              hipStream_t stream)
{
    const float* x      = (const float*)d_in[0];
    const float* w_qkv  = (const float*)d_in[1];
    const float* bias_t = (const float*)d_in[2];
    const float* w_h    = (const float*)d_in[3];
    const float* b_h    = (const float*)d_in[4];
    const float* w_v    = (const float*)d_in[5];
    const float* b_v    = (const float*)d_in[6];
    const float* w_dw   = (const float*)d_in[7];
    const float* bn_g   = (const float*)d_in[8];
    const float* bn_b   = (const float*)d_in[9];
    const float* bn_m   = (const float*)d_in[10];
    const float* bn_v   = (const float*)d_in[11];
    const float* w_pw   = (const float*)d_in[12];
    float* out = (float*)d_out;

    u16* wsu = (u16*)d_ws;
    const u16* XPu = wsu;
    const u16* ZPu = wsu + ZP_OFF / 2;
    const u16* WTu = wsu + WT_OFF / 2;
    const u16* WPu = wsu + WPW_OFF / 2;
    const u16* WQu = wsu + WQ_OFF / 2;
    const float* BFu = (const float*)(wsu + BIAS_OFF / 2);

    // wprep -> attn(MFMA) -> halo -> sepconv(MFMA) -> dwbn -> pw(MFMA)
    wprep_kernel<<<5984, 256, 0, stream>>>(w_h, w_v, w_pw, w_qkv, bias_t, wsu);
    attn_mfma<<<2048, 256, 0, stream>>>(x, WQu, BFu, wsu);
    halo_kernel<<<6048, 256, 0, stream>>>(wsu);
    sepconv_mfma<<<504, 512, 0, stream>>>(XPu, WTu, ZPu, b_h, b_v, out);
    dwbn_kernel<<<dim3(8, 32, 512), 256, 0, stream>>>(out, w_dw, bn_g, bn_b, bn_m, bn_v,
                                                      (__hip_bfloat16*)d_ws);
    pw_mfma<<<504, 512, 0, stream>>>(wsu, WPu, out);
}

// Round 9
// 765.428 us; speedup vs baseline: 6.0122x; 6.0122x over previous
//
#include <hip/hip_runtime.h>
#include <hip/hip_bf16.h>

#define HC 252
#define WC 252
#define CD 256
#define NHEADS 16

// XP padded image: [b][ci][h 0..251][wp 0..263], wp = w_img + 4
#define XP_W 264
#define XP_HW (252*264)
#define XP_CHW (256*252*264)

typedef unsigned short u16;
typedef unsigned int u32;
typedef __attribute__((ext_vector_type(8))) short bf16x8;
typedef __attribute__((ext_vector_type(4))) float f32x4;
typedef __attribute__((ext_vector_type(4))) u32 u32x4;
typedef __attribute__((ext_vector_type(2))) u32 u32x2;

// ---- workspace layout (bytes) ----
#define XP_BYTES (2u * (unsigned)XP_CHW * 2u)      // 68,124,672
#define ZP_OFF   XP_BYTES
#define ZP_BYTES 409600u
#define WT_OFF   (ZP_OFF + ZP_BYTES)
#define WT_ELEMS (128*8192)                        // 1,048,576 bf16 [s][l(swz)][8]
#define WPW_OFF  (WT_OFF + (unsigned)WT_ELEMS*2u)
#define WPW_ELEMS (8*8192)                         // 65,536 bf16
#define WQ_OFF   (WPW_OFF + (unsigned)WPW_ELEMS*2u)
#define WQ_ELEMS (768*256)                         // 196,608 bf16
#define BIAS_OFF (WQ_OFF + (unsigned)WQ_ELEMS*2u)

__device__ __forceinline__ u16 bfu(float f) {
    __hip_bfloat16 h = __float2bfloat16(f);
    return *(reinterpret_cast<u16*>(&h));
}
__device__ __forceinline__ u32 pack2(float a, float b) {
    return (u32)bfu(a) | ((u32)bfu(b) << 16);
}
__device__ __forceinline__ float bf2f(u16 v) {
    union { u32 u; float f; } cv; cv.u = ((u32)v) << 16; return cv.f;
}

// ---------------- Kernel A: fused qkv + window attention (MFMA) --------------
// grid 2048 (XCD-swizzled), 256 threads (4 waves, 4 heads/wave, sequential).
__global__ __launch_bounds__(256, 2) void attn_mfma(
    const float* __restrict__ x, const u16* __restrict__ WQ,
    const float* __restrict__ BIASF, u16* __restrict__ xp)
{
    __shared__ __align__(16) char smem[73728];

    const int bid = blockIdx.x;
    const int zz = (bid & 7) * 256 + (bid >> 3);   // XCD-bijective swizzle
    const int wx = zz & 31, wy = (zz >> 5) & 31, b = zz >> 10;
    const int tid = threadIdx.x;
    const int lane = tid & 63, wid = tid >> 6;
    const int g = lane >> 4, li = lane & 15;

    // ---- stage Xwin (fp32 x -> bf16 LDS, transposed, reflect-padded) ----
    {
        int ci = tid;
        const float* srcc = x + (size_t)(b * 256 + ci) * (HC * WC);
        #pragma unroll
        for (int r = 0; r < 8; ++r) {
            int h = wy * 8 + r; if (h >= HC) h = 2 * HC - 2 - h;
            const float* src = srcc + h * WC;
            float v[8];
            if (wx == 31) {
                #pragma unroll
                for (int c = 0; c < 8; ++c) {
                    int w = 248 + c; if (w >= WC) w = 2 * WC - 2 - w;
                    v[c] = src[w];
                }
            } else {
                float4 f0 = *(const float4*)(src + wx * 8);
                float4 f1 = *(const float4*)(src + wx * 8 + 4);
                v[0]=f0.x; v[1]=f0.y; v[2]=f0.z; v[3]=f0.w;
                v[4]=f1.x; v[5]=f1.y; v[6]=f1.z; v[7]=f1.w;
            }
            #pragma unroll
            for (int c = 0; c < 8; ++c) {
                int pos = r * 8 + c;
                int byte = pos * 512 + ((ci * 2) ^ ((pos & 7) << 4));
                *(u16*)(smem + byte) = bfu(v[c]);
            }
        }
    }
    __syncthreads();

    const int WB = 32768 + wid * 10240;
    char* Qb = smem + WB;
    char* Kb = smem + WB + 2048;
    char* Vb = smem + WB + 4096;
    char* Pb = smem + WB + 6144;

    const bf16x8 zf = {0,0,0,0,0,0,0,0};

    #pragma unroll 1
    for (int hh = 0; hh < 4; ++hh) {
        const int head = wid * 4 + hh;

        f32x4 acc[3][4];
        #pragma unroll
        for (int p = 0; p < 3; ++p)
            #pragma unroll
            for (int nf = 0; nf < 4; ++nf) acc[p][nf] = (f32x4){0.f,0.f,0.f,0.f};

        for (int ks = 0; ks < 8; ++ks) {
            bf16x8 bx[4];
            #pragma unroll
            for (int nf = 0; nf < 4; ++nf) {
                int pos = 16 * nf + li;
                int byte = pos * 512 + ((ks * 64 + 16 * g) ^ ((pos & 7) << 4));
                bx[nf] = *(const bf16x8*)(smem + byte);
            }
            bf16x8 aw[3];
            #pragma unroll
            for (int p = 0; p < 3; ++p) {
                int o = p * 256 + head * 16 + li;
                aw[p] = *(const bf16x8*)(WQ + o * 256 + ks * 32 + 8 * g);
            }
            __builtin_amdgcn_s_setprio(1);
            #pragma unroll
            for (int p = 0; p < 3; ++p)
                #pragma unroll
                for (int nf = 0; nf < 4; ++nf)
                    acc[p][nf] = __builtin_amdgcn_mfma_f32_16x16x32_bf16(aw[p], bx[nf], acc[p][nf], 0, 0, 0);
            __builtin_amdgcn_s_setprio(0);
        }

        #pragma unroll
        for (int p = 0; p < 3; ++p) {
            if (p < 2) {
                char* base = (p == 0) ? Qb : Kb;
                #pragma unroll
                for (int nf = 0; nf < 4; ++nf) {
                    int pos = 16 * nf + li;
                    u32 lo = pack2(acc[p][nf][0], acc[p][nf][1]);
                    u32 hi = pack2(acc[p][nf][2], acc[p][nf][3]);
                    int byte = pos * 32 + ((8 * g) ^ (((pos >> 2) & 1) << 4));
                    *(u32x2*)(base + byte) = (u32x2){lo, hi};
                }
            } else {
                #pragma unroll
                for (int nf = 0; nf < 4; ++nf) {
                    int pos = 16 * nf + li;
                    #pragma unroll
                    for (int r = 0; r < 4; ++r) {
                        int d = 4 * g + r;
                        int byte = (pos >> 3) * 256 + d * 16 + (pos & 7) * 2;
                        *(u16*)(Vb + byte) = bfu(acc[p][nf][r]);
                    }
                }
            }
        }

        f32x4 s[4][4];
        #pragma unroll
        for (int mf = 0; mf < 4; ++mf)
            #pragma unroll
            for (int nf = 0; nf < 4; ++nf) s[mf][nf] = (f32x4){0.f,0.f,0.f,0.f};
        bf16x8 bk[4];
        #pragma unroll
        for (int nf = 0; nf < 4; ++nf) {
            int pos = 16 * nf + li;
            bk[nf] = (g < 2) ? *(const bf16x8*)(Kb + pos * 32 + ((16 * g) ^ (((pos >> 2) & 1) << 4))) : zf;
        }
        __builtin_amdgcn_s_setprio(1);
        #pragma unroll
        for (int mf = 0; mf < 4; ++mf) {
            int pos = 16 * mf + li;
            bf16x8 aq = (g < 2) ? *(const bf16x8*)(Qb + pos * 32 + ((16 * g) ^ (((pos >> 2) & 1) << 4))) : zf;
            #pragma unroll
            for (int nf = 0; nf < 4; ++nf)
                s[mf][nf] = __builtin_amdgcn_mfma_f32_16x16x32_bf16(aq, bk[nf], s[mf][nf], 0, 0, 0);
        }
        __builtin_amdgcn_s_setprio(0);

        f32x4 e[4][4];
        f32x4 rs[4];
        #pragma unroll
        for (int mf = 0; mf < 4; ++mf) rs[mf] = (f32x4){0.f,0.f,0.f,0.f};
        #pragma unroll
        for (int mf = 0; mf < 4; ++mf)
            #pragma unroll
            for (int nf = 0; nf < 4; ++nf) {
                f32x4 b4 = *(const f32x4*)(BIASF + (((head * 4 + mf) * 4 + nf) * 64 + lane) * 4);
                #pragma unroll
                for (int r = 0; r < 4; ++r) {
                    float ev = __expf(s[mf][nf][r] * 0.25f + b4[r]);
                    e[mf][nf][r] = ev;
                    rs[mf][r] += ev;
                }
            }
        #pragma unroll
        for (int mf = 0; mf < 4; ++mf)
            #pragma unroll
            for (int r = 0; r < 4; ++r) {
                float t = rs[mf][r];
                t += __shfl_xor(t, 1); t += __shfl_xor(t, 2);
                t += __shfl_xor(t, 4); t += __shfl_xor(t, 8);
                rs[mf][r] = t;
            }

        f32x4 o[4];
        #pragma unroll
        for (int mf = 0; mf < 4; ++mf) o[mf] = (f32x4){0.f,0.f,0.f,0.f};
        const bool even = !(lane & 1);
        #pragma unroll
        for (int hf = 0; hf < 2; ++hf) {
            #pragma unroll
            for (int mf = 0; mf < 4; ++mf)
                #pragma unroll
                for (int nfl = 0; nfl < 2; ++nfl) {
                    f32x4 ee = e[mf][2 * hf + nfl];
                    float p0 = __shfl_xor(ee[0], 1), p1 = __shfl_xor(ee[1], 1);
                    float p2 = __shfl_xor(ee[2], 1), p3 = __shfl_xor(ee[3], 1);
                    int jl = 16 * nfl + (li & ~1);
                    u32 w0, w1; int r0;
                    if (even) { w0 = pack2(ee[0], p0); w1 = pack2(ee[1], p1); r0 = 0; }
                    else      { w0 = pack2(p2, ee[2]); w1 = pack2(p3, ee[3]); r0 = 2; }
                    int i0 = 16 * mf + 4 * g + r0, i1 = i0 + 1;
                    *(u32*)(Pb + i0 * 64 + ((2 * jl) ^ ((i0 & 3) << 4))) = w0;
                    *(u32*)(Pb + i1 * 64 + ((2 * jl) ^ ((i1 & 3) << 4))) = w1;
                }
            bf16x8 bv = *(const bf16x8*)(Vb + (4 * hf + g) * 256 + li * 16);
            __builtin_amdgcn_s_setprio(1);
            #pragma unroll
            for (int mf = 0; mf < 4; ++mf) {
                int i = 16 * mf + li;
                bf16x8 ap = *(const bf16x8*)(Pb + i * 64 + ((16 * g) ^ ((i & 3) << 4)));
                o[mf] = __builtin_amdgcn_mfma_f32_16x16x32_bf16(ap, bv, o[mf], 0, 0, 0);
            }
            __builtin_amdgcn_s_setprio(0);
        }

        #pragma unroll
        for (int mf = 0; mf < 4; ++mf) {
            int h = wy * 8 + 2 * mf + (g >> 1);
            int wbase = wx * 8 + 4 * (g & 1);
            if (h < HC && wbase < WC) {
                float v0 = o[mf][0] / rs[mf][0], v1 = o[mf][1] / rs[mf][1];
                float v2 = o[mf][2] / rs[mf][2], v3 = o[mf][3] / rs[mf][3];
                size_t idx = ((size_t)(b * 256 + head * 16 + li) * HC + h) * XP_W + wbase + 4;
                *(u32x2*)(xp + idx) = (u32x2){pack2(v0, v1), pack2(v2, v3)};
            }
        }
    }
}

// ---------------- weight prep: WT (pre-swizzled), WP (pre-swizzled), ZP, WQ, BIASF
__global__ __launch_bounds__(256) void wprep_kernel(
    const float* __restrict__ wh, const float* __restrict__ wv,
    const float* __restrict__ wpw, const float* __restrict__ wqkv,
    const float* __restrict__ btab, u16* __restrict__ wsu)
{
    int i = blockIdx.x * 256 + threadIdx.x;
    u16* WT = wsu + WT_OFF / 2;
    u16* WP = wsu + WPW_OFF / 2;
    u16* ZP = wsu + ZP_OFF / 2;
    u16* WQp = wsu + WQ_OFF / 2;
    float* BF = (float*)(wsu + BIAS_OFF / 2);
    if (i < WT_ELEMS) {
        // WT[s][l][8]: LDS chunk l holds weight chunk c = l ^ ((l>>8&3)<<1)
        // (involution; reads use As[kb*256 + (co ^ (kb<<1))])
        int j = i & 7, l = (i >> 3) & 1023, s = i >> 13;
        int kb = (l >> 8) & 3;
        int co = (l & 255) ^ (kb << 1);
        float v = (s < 64) ? wh[co * 2048 + s * 32 + kb * 8 + j]
                           : wv[co * 2048 + (s - 64) * 32 + kb * 8 + j];
        WT[i] = bfu(v);
    } else if (i < WT_ELEMS + WPW_ELEMS) {
        int i2 = i - WT_ELEMS;
        int j = i2 & 7, l = (i2 >> 3) & 1023, s = i2 >> 13;
        int kb = (l >> 8) & 3;
        int co = (l & 255) ^ (kb << 1);
        WP[i2] = bfu(wpw[co * 256 + s * 32 + kb * 8 + j]);
    } else if (i < WT_ELEMS + WPW_ELEMS + (int)(ZP_BYTES / 2)) {
        ZP[i - WT_ELEMS - WPW_ELEMS] = 0;
    } else if (i < WT_ELEMS + WPW_ELEMS + (int)(ZP_BYTES / 2) + WQ_ELEMS) {
        int i4 = i - WT_ELEMS - WPW_ELEMS - (int)(ZP_BYTES / 2);
        WQp[i4] = bfu(wqkv[i4]);
    } else {
        int i5 = i - WT_ELEMS - WPW_ELEMS - (int)(ZP_BYTES / 2) - WQ_ELEMS;
        if (i5 < 16384) {
            int lane = i5 & 63, nf = (i5 >> 6) & 3, mf = (i5 >> 8) & 3, head = i5 >> 10;
            int gg = lane >> 4, ll = lane & 15;
            #pragma unroll
            for (int r = 0; r < 4; ++r) {
                int row = 16 * mf + 4 * gg + r;
                int col = 16 * nf + ll;
                int dy = (row >> 3) - (col >> 3) + 7;
                int dx = (row & 7) - (col & 7) + 7;
                BF[i5 * 4 + r] = btab[(dy * 15 + dx) * NHEADS + head];
            }
        }
    }
}

// ---------------- halo fill for XP: wp 0..3, 256..263 ------------------------
__global__ __launch_bounds__(256) void halo_kernel(u16* __restrict__ xp)
{
    int i = blockIdx.x * 256 + threadIdx.x;
    if (i >= 129024 * 12) return;
    int row = i / 12, c = i % 12;
    int wp = (c < 4) ? c : 252 + c;
    u16 v = 0;
    if (wp == 256) v = xp[row * XP_W + 254];
    xp[row * XP_W + wp] = v;
}

// ---------------- Kernel B: sepconv bf16 MFMA, K=4096 ------------------------
// grid 504 = (b,h), XCD-swizzled. 512 thr, 8 waves of 128co x 64w.
// A-stage via global_load_lds (WT pre-swizzled, linear LDS dest). P out bf16.
__global__ __launch_bounds__(512, 2) void sepconv_mfma(
    const u16* __restrict__ xp, const u16* __restrict__ WT,
    const u16* __restrict__ ZP,
    const float* __restrict__ b_h, const float* __restrict__ b_v,
    u16* __restrict__ P)
{
    __shared__ __align__(16) u16 As[2][8192];   // [kb][co^swz][8] via WT layout
    __shared__ __align__(16) u16 Bs[2][256 * 36];

    const int bid = blockIdx.x;                 // 504 = 8*63, bijective swizzle
    const int zz = (bid & 7) * 63 + (bid >> 3);
    const int h = zz % HC, b = zz / HC;
    const int tid = threadIdx.x;
    const int lane = tid & 63, wid = tid >> 6;
    const int wr = wid >> 2, wc = wid & 3;
    const int cq = lane & 15, kb = lane >> 4;

    const int wl2 = (tid & 127) * 2;
    const int oc = tid >> 7;

    const u16* hcur[8];
    int hstep[8];
    #pragma unroll
    for (int t = 0; t < 8; ++t) {
        int j = h + t - 3;
        bool valid = (j >= 0 && j <= 252);
        int jr = (j == 252) ? 250 : j;
        hcur[t] = valid ? (xp + (size_t)b * XP_CHW + (size_t)jr * XP_W) : ZP;
        hstep[t] = valid ? 4 * XP_HW : 0;
    }
    const u16* vbase = xp + (size_t)b * XP_CHW + (size_t)h * XP_W;
    const int hvoff = oc * XP_HW + wl2 + 4;

    const int bw0 = wl2 * 36 + oc * 8;
    const int bw1 = bw0 + 36;

    f32x4 acc[8][4];
    #pragma unroll
    for (int m = 0; m < 8; ++m)
        #pragma unroll
        for (int n = 0; n < 4; ++n) acc[m][n] = (f32x4){0.f, 0.f, 0.f, 0.f};

    u32 rB[8];

#define SC_GLA(t, buf)                                                         \
    if ((t) < 128) {                                                           \
        __builtin_amdgcn_global_load_lds(                                      \
            (const u32*)(WT + (size_t)(t) * 8192 + (size_t)tid * 8),           \
            (u32*)&As[buf][(size_t)tid * 8], 16, 0, 0);                        \
        __builtin_amdgcn_global_load_lds(                                      \
            (const u32*)(WT + (size_t)(t) * 8192 + (size_t)(512 + tid) * 8),   \
            (u32*)&As[buf][(size_t)(512 + tid) * 8], 16, 0, 0);                \
    }

#define SC_ADV()                                                               \
    { _Pragma("unroll") for (int tt = 0; tt < 8; ++tt) hcur[tt] += hstep[tt]; }

#define SC_LOADB(t)                                                            \
    if ((t) < 128) {                                                           \
        if ((t) < 64) {                                                        \
            _Pragma("unroll") for (int tt = 0; tt < 8; ++tt)                   \
                rB[tt] = *(const u32*)(hcur[tt] + hvoff);                      \
        } else {                                                               \
            int off_ = (((t) - 64) * 4 + oc) * XP_HW + wl2;                    \
            _Pragma("unroll") for (int l = 0; l < 6; ++l)                      \
                rB[l] = *(const u32*)(vbase + off_ + 2 * l);                   \
        }                                                                      \
    }

#define SC_WRITEB(t, buf)                                                      \
    if ((t) < 128) {                                                           \
        union { bf16x8 v; u32 u[4]; } p0_, p1_;                                \
        if ((t) < 64) {                                                        \
            _Pragma("unroll") for (int q = 0; q < 4; ++q) {                    \
                p0_.u[q] = __builtin_amdgcn_perm(rB[2*q+1], rB[2*q], 0x05040100u); \
                p1_.u[q] = __builtin_amdgcn_perm(rB[2*q+1], rB[2*q], 0x07060302u); \
            }                                                                  \
        } else {                                                               \
            _Pragma("unroll") for (int q = 0; q < 4; ++q)                      \
                p0_.u[q] = __builtin_amdgcn_alignbit(rB[q+1], rB[q], 16);      \
            p1_.u[0] = rB[1]; p1_.u[1] = rB[2]; p1_.u[2] = rB[3]; p1_.u[3] = rB[4]; \
        }                                                                      \
        *(bf16x8*)&Bs[buf][bw0] = p0_.v;                                       \
        *(bf16x8*)&Bs[buf][bw1] = p1_.v;                                       \
    }

    // ---- prologue: step 0 -> LDS[0] (hcur at step-0 positions) ----
    SC_GLA(0, 0)
    SC_LOADB(0)
    SC_WRITEB(0, 0)

    #pragma unroll 1
    for (int s = 0; s < 128; ++s) {
        const int cur = s & 1;
        const int nxt = cur ^ 1;
        const int s1 = s + 1;
        __syncthreads();                 // As[cur] (gload_lds) drained here
        if (s1 < 64) { SC_ADV() }        // advance BEFORE loading step s+1 (R8 bug fix)
        SC_LOADB(s1)                     // B regs for s+1 (oldest vmem first)
        SC_GLA(s1, nxt)                  // A for s+1 direct to LDS, in flight
        {
            bf16x8 af[8], bfr[4];
            #pragma unroll
            for (int m = 0; m < 8; ++m) {
                int row = wr * 128 + m * 16 + cq;
                af[m] = *(const bf16x8*)&As[cur][(kb * 256 + (row ^ (kb << 1))) * 8];
            }
            #pragma unroll
            for (int n = 0; n < 4; ++n)
                bfr[n] = *(const bf16x8*)&Bs[cur][(wc * 64 + n * 16 + cq) * 36 + kb * 8];
            #pragma unroll
            for (int m = 0; m < 8; ++m)
                #pragma unroll
                for (int n = 0; n < 4; ++n)
                    acc[m][n] = __builtin_amdgcn_mfma_f32_16x16x32_bf16(af[m], bfr[n], acc[m][n], 0, 0, 0);
        }
        SC_WRITEB(s1, nxt)
    }

#undef SC_GLA
#undef SC_ADV
#undef SC_LOADB
#undef SC_WRITEB

    // ---- epilogue: bias + bf16 store ----
    const int rq = lane >> 4, cc = lane & 15;
    #pragma unroll
    for (int m = 0; m < 8; ++m) {
        int cgb = wr * 128 + m * 16 + rq * 4;
        float bias[4];
        #pragma unroll
        for (int rr = 0; rr < 4; ++rr) bias[rr] = b_h[cgb + rr] + b_v[cgb + rr];
        #pragma unroll
        for (int n = 0; n < 4; ++n) {
            int wg = wc * 64 + n * 16 + cc;
            if (wg < WC) {
                #pragma unroll
                for (int rr = 0; rr < 4; ++rr)
                    P[((size_t)(b * CD + cgb + rr) * HC + h) * WC + wg] = bfu(acc[m][n][rr] + bias[rr]);
            }
        }
    }
}

// ---------------- Kernel C: depthwise 8x8 conv + BN (bf16 in) -> bf16 Y ------
__global__ __launch_bounds__(256) void dwbn_kernel(
    const u16* __restrict__ P, const float* __restrict__ w_dw,
    const float* __restrict__ gamma, const float* __restrict__ beta,
    const float* __restrict__ mean, const float* __restrict__ var,
    __hip_bfloat16* __restrict__ Yb)
{
    __shared__ float ps[15][42];
    __shared__ float wd[64];
    const int bw = blockIdx.x, bh = blockIdx.y, bz = blockIdx.z;
    const int b = bz >> 8, c = bz & 255;
    const int h0 = bh * 8, w0 = bw * 32;
    const int tid = threadIdx.x;
    if (tid < 64) wd[tid] = w_dw[c * 64 + tid];
    for (int it = 0; it < 3; ++it) {
        int flat = tid + it * 256;
        if (flat < 630) {
            int row = flat / 42, col = flat % 42;
            int j = h0 - 3 + row, wcol = w0 - 3 + col;
            float v = 0.f;
            if (j >= 0 && j <= HC && wcol >= 0 && wcol <= WC) {
                int jr = (j == HC) ? (HC - 2) : j;
                int wr2 = (wcol == WC) ? (WC - 2) : wcol;
                v = bf2f(P[((size_t)(b * CD + c) * HC + jr) * WC + wr2]);
            }
            ps[row][col] = v;
        }
    }
    __syncthreads();
    const int r = tid >> 5, cc = tid & 31;
    const int h = h0 + r, w = w0 + cc;
    if (h < HC && w < WC) {
        float s = 0.f;
        #pragma unroll
        for (int u = 0; u < 8; ++u)
            #pragma unroll
            for (int v2 = 0; v2 < 8; ++v2)
                s += wd[u * 8 + v2] * ps[r + u][cc + v2];
        const float inv = gamma[c] * rsqrtf(var[c] + 1e-5f);
        Yb[((b * CD + c) * HC + h) * WC + w] = __float2bfloat16(s * inv + (beta[c] - mean[c] * inv));
    }
}

// ---------------- Kernel D: pointwise 1x1, bf16 MFMA, K=256 ------------------
// grid 504 = (b,h), XCD-swizzled. 512 thr, 8 waves of 128co x 64w.
__global__ __launch_bounds__(512, 2) void pw_mfma(
    const u16* __restrict__ Y, const u16* __restrict__ WP,
    float* __restrict__ O)
{
    __shared__ __align__(16) u16 As[2][8192];
    __shared__ __align__(16) u16 Bs[2][256 * 36];

    const int bid = blockIdx.x;
    const int zz = (bid & 7) * 63 + (bid >> 3);
    const int h = zz % HC, b = zz / HC;
    const int tid = threadIdx.x;
    const int lane = tid & 63, wid = tid >> 6;
    const int wr = wid >> 2, wc = wid & 3;
    const int cq = lane & 15, kb = lane >> 4;

    const int wl2 = (tid & 127) * 2;
    const int oc = tid >> 7;

    const u16* yb = Y + ((size_t)(b * 256 + oc * 8) * HC + h) * WC + wl2;

    const int bw0 = wl2 * 36 + oc * 8;
    const int bw1 = bw0 + 36;

    f32x4 acc[8][4];
    #pragma unroll
    for (int m = 0; m < 8; ++m)
        #pragma unroll
        for (int n = 0; n < 4; ++n) acc[m][n] = (f32x4){0.f, 0.f, 0.f, 0.f};

    u32 rB[8];

#define PW_GLA(t, buf)                                                         \
    if ((t) < 8) {                                                             \
        __builtin_amdgcn_global_load_lds(                                      \
            (const u32*)(WP + (size_t)(t) * 8192 + (size_t)tid * 8),           \
            (u32*)&As[buf][(size_t)tid * 8], 16, 0, 0);                        \
        __builtin_amdgcn_global_load_lds(                                      \
            (const u32*)(WP + (size_t)(t) * 8192 + (size_t)(512 + tid) * 8),   \
            (u32*)&As[buf][(size_t)(512 + tid) * 8], 16, 0, 0);                \
    }

#define PW_LOADB(t)                                                            \
    if ((t) < 8) {                                                             \
        _Pragma("unroll") for (int j = 0; j < 8; ++j)                          \
            rB[j] = *(const u32*)(yb + (size_t)((t) * 32 + j) * (HC * WC));    \
    }

#define PW_WRITEB(t, buf)                                                      \
    if ((t) < 8) {                                                             \
        union { bf16x8 v; u32 u[4]; } p0_, p1_;                                \
        _Pragma("unroll") for (int q = 0; q < 4; ++q) {                        \
            p0_.u[q] = __builtin_amdgcn_perm(rB[2*q+1], rB[2*q], 0x05040100u); \
            p1_.u[q] = __builtin_amdgcn_perm(rB[2*q+1], rB[2*q], 0x07060302u); \
        }                                                                      \
        *(bf16x8*)&Bs[buf][bw0] = p0_.v;                                       \
        *(bf16x8*)&Bs[buf][bw1] = p1_.v;                                       \
    }

    // ---- prologue ----
    PW_GLA(0, 0)
    PW_LOADB(0)
    PW_WRITEB(0, 0)

    #pragma unroll 1
    for (int s = 0; s < 8; ++s) {
        const int cur = s & 1;
        const int nxt = cur ^ 1;
        const int s1 = s + 1;
        __syncthreads();
        PW_LOADB(s1)
        PW_GLA(s1, nxt)
        {
            bf16x8 af[8], bfr[4];
            #pragma unroll
            for (int m = 0; m < 8; ++m) {
                int row = wr * 128 + m * 16 + cq;
                af[m] = *(const bf16x8*)&As[cur][(kb * 256 + (row ^ (kb << 1))) * 8];
            }
            #pragma unroll
            for (int n = 0; n < 4; ++n)
                bfr[n] = *(const bf16x8*)&Bs[cur][(wc * 64 + n * 16 + cq) * 36 + kb * 8];
            #pragma unroll
            for (int m = 0; m < 8; ++m)
                #pragma unroll
                for (int n = 0; n < 4; ++n)
                    acc[m][n] = __builtin_amdgcn_mfma_f32_16x16x32_bf16(af[m], bfr[n], acc[m][n], 0, 0, 0);
        }
        PW_WRITEB(s1, nxt)
    }

#undef PW_GLA
#undef PW_LOADB
#undef PW_WRITEB

    const int rq = lane >> 4, cc = lane & 15;
    #pragma unroll
    for (int m = 0; m < 8; ++m) {
        int cgb = wr * 128 + m * 16 + rq * 4;
        #pragma unroll
        for (int n = 0; n < 4; ++n) {
            int wg = wc * 64 + n * 16 + cc;
            if (wg < WC) {
                #pragma unroll
                for (int rr = 0; rr < 4; ++rr)
                    O[((size_t)(b * CD + cgb + rr) * HC + h) * WC + wg] = acc[m][n][rr];
            }
        }
    }
}

extern "C" void kernel_launch(void* const* d_in, const int* in_sizes, int n_in,
                              void* d_out, int out_size, void* d_ws, size_t ws_size,
                              hipStream_t stream)
{
    const float* x      = (const float*)d_in[0];
    const float* w_qkv  = (const float*)d_in[1];
    const float* bias_t = (const float*)d_in[2];
    const float* w_h    = (const float*)d_in[3];
    const float* b_h    = (const float*)d_in[4];
    const float* w_v    = (const float*)d_in[5];
    const float* b_v    = (const float*)d_in[6];
    const float* w_dw   = (const float*)d_in[7];
    const float* bn_g   = (const float*)d_in[8];
    const float* bn_b   = (const float*)d_in[9];
    const float* bn_m   = (const float*)d_in[10];
    const float* bn_v   = (const float*)d_in[11];
    const float* w_pw   = (const float*)d_in[12];
    float* out = (float*)d_out;

    u16* wsu = (u16*)d_ws;
    const u16* XPu = wsu;
    const u16* ZPu = wsu + ZP_OFF / 2;
    const u16* WTu = wsu + WT_OFF / 2;
    const u16* WPu = wsu + WPW_OFF / 2;
    const u16* WQu = wsu + WQ_OFF / 2;
    const float* BFu = (const float*)(wsu + BIAS_OFF / 2);

    // wprep -> attn(MFMA) -> halo -> sepconv(MFMA, bf16 P) -> dwbn -> pw(MFMA)
    wprep_kernel<<<5984, 256, 0, stream>>>(w_h, w_v, w_pw, w_qkv, bias_t, wsu);
    attn_mfma<<<2048, 256, 0, stream>>>(x, WQu, BFu, wsu);
    halo_kernel<<<6048, 256, 0, stream>>>(wsu);
    sepconv_mfma<<<504, 512, 0, stream>>>(XPu, WTu, ZPu, b_h, b_v, (u16*)d_out);
    dwbn_kernel<<<dim3(8, 32, 512), 256, 0, stream>>>((const u16*)d_out, w_dw, bn_g, bn_b,
                                                      bn_m, bn_v, (__hip_bfloat16*)d_ws);
    pw_mfma<<<504, 512, 0, stream>>>(wsu, WPu, out);
}

// Round 10
// 678.113 us; speedup vs baseline: 6.7863x; 1.1288x over previous
//
#include <hip/hip_runtime.h>
#include <hip/hip_bf16.h>

#define HC 252
#define WC 252
#define CD 256
#define NHEADS 16

// XP padded image: [b][ci][h 0..251][wp 0..263], wp = w_img + 4
#define XP_W 264
#define XP_HW (252*264)
#define XP_CHW (256*252*264)

typedef unsigned short u16;
typedef unsigned int u32;
typedef __attribute__((ext_vector_type(8))) short bf16x8;
typedef __attribute__((ext_vector_type(4))) float f32x4;
typedef __attribute__((ext_vector_type(4))) u32 u32x4;
typedef __attribute__((ext_vector_type(2))) u32 u32x2;

// ---- workspace layout (bytes) ----
#define XP_BYTES (2u * (unsigned)XP_CHW * 2u)      // 68,124,672
#define ZP_OFF   XP_BYTES
#define ZP_BYTES 409600u
#define WT_OFF   (ZP_OFF + ZP_BYTES)
#define WT_ELEMS (128*8192)                        // 1,048,576 bf16 [s][l(swz)][8]
#define WPW_OFF  (WT_OFF + (unsigned)WT_ELEMS*2u)
#define WPW_ELEMS (8*8192)                         // 65,536 bf16
#define WQ_OFF   (WPW_OFF + (unsigned)WPW_ELEMS*2u)
#define WQ_ELEMS (768*256)                         // 196,608 bf16
#define BIAS_OFF (WQ_OFF + (unsigned)WQ_ELEMS*2u)

__device__ __forceinline__ u16 bfu(float f) {
    __hip_bfloat16 h = __float2bfloat16(f);
    return *(reinterpret_cast<u16*>(&h));
}
__device__ __forceinline__ u32 pack2(float a, float b) {
    return (u32)bfu(a) | ((u32)bfu(b) << 16);
}
__device__ __forceinline__ float bf2f(u16 v) {
    union { u32 u; float f; } cv; cv.u = ((u32)v) << 16; return cv.f;
}

// ---------------- Kernel A: fused qkv + window attention (MFMA) --------------
// grid 2048 (XCD-swizzled), 256 threads (4 waves, 4 heads/wave, sequential).
__global__ __launch_bounds__(256, 2) void attn_mfma(
    const float* __restrict__ x, const u16* __restrict__ WQ,
    const float* __restrict__ BIASF, u16* __restrict__ xp)
{
    __shared__ __align__(16) char smem[73728];

    const int bid = blockIdx.x;
    const int zz = (bid & 7) * 256 + (bid >> 3);   // XCD-bijective swizzle
    const int wx = zz & 31, wy = (zz >> 5) & 31, b = zz >> 10;
    const int tid = threadIdx.x;
    const int lane = tid & 63, wid = tid >> 6;
    const int g = lane >> 4, li = lane & 15;

    // ---- stage Xwin (fp32 x -> bf16 LDS, transposed, reflect-padded) ----
    {
        int ci = tid;
        const float* srcc = x + (size_t)(b * 256 + ci) * (HC * WC);
        #pragma unroll
        for (int r = 0; r < 8; ++r) {
            int h = wy * 8 + r; if (h >= HC) h = 2 * HC - 2 - h;
            const float* src = srcc + h * WC;
            float v[8];
            if (wx == 31) {
                #pragma unroll
                for (int c = 0; c < 8; ++c) {
                    int w = 248 + c; if (w >= WC) w = 2 * WC - 2 - w;
                    v[c] = src[w];
                }
            } else {
                float4 f0 = *(const float4*)(src + wx * 8);
                float4 f1 = *(const float4*)(src + wx * 8 + 4);
                v[0]=f0.x; v[1]=f0.y; v[2]=f0.z; v[3]=f0.w;
                v[4]=f1.x; v[5]=f1.y; v[6]=f1.z; v[7]=f1.w;
            }
            #pragma unroll
            for (int c = 0; c < 8; ++c) {
                int pos = r * 8 + c;
                int byte = pos * 512 + ((ci * 2) ^ ((pos & 7) << 4));
                *(u16*)(smem + byte) = bfu(v[c]);
            }
        }
    }
    __syncthreads();

    const int WB = 32768 + wid * 10240;
    char* Qb = smem + WB;
    char* Kb = smem + WB + 2048;
    char* Vb = smem + WB + 4096;
    char* Pb = smem + WB + 6144;

    const bf16x8 zf = {0,0,0,0,0,0,0,0};

    #pragma unroll 1
    for (int hh = 0; hh < 4; ++hh) {
        const int head = wid * 4 + hh;

        f32x4 acc[3][4];
        #pragma unroll
        for (int p = 0; p < 3; ++p)
            #pragma unroll
            for (int nf = 0; nf < 4; ++nf) acc[p][nf] = (f32x4){0.f,0.f,0.f,0.f};

        for (int ks = 0; ks < 8; ++ks) {
            bf16x8 bx[4];
            #pragma unroll
            for (int nf = 0; nf < 4; ++nf) {
                int pos = 16 * nf + li;
                int byte = pos * 512 + ((ks * 64 + 16 * g) ^ ((pos & 7) << 4));
                bx[nf] = *(const bf16x8*)(smem + byte);
            }
            bf16x8 aw[3];
            #pragma unroll
            for (int p = 0; p < 3; ++p) {
                int o = p * 256 + head * 16 + li;
                aw[p] = *(const bf16x8*)(WQ + o * 256 + ks * 32 + 8 * g);
            }
            __builtin_amdgcn_s_setprio(1);
            #pragma unroll
            for (int p = 0; p < 3; ++p)
                #pragma unroll
                for (int nf = 0; nf < 4; ++nf)
                    acc[p][nf] = __builtin_amdgcn_mfma_f32_16x16x32_bf16(aw[p], bx[nf], acc[p][nf], 0, 0, 0);
            __builtin_amdgcn_s_setprio(0);
        }

        #pragma unroll
        for (int p = 0; p < 3; ++p) {
            if (p < 2) {
                char* base = (p == 0) ? Qb : Kb;
                #pragma unroll
                for (int nf = 0; nf < 4; ++nf) {
                    int pos = 16 * nf + li;
                    u32 lo = pack2(acc[p][nf][0], acc[p][nf][1]);
                    u32 hi = pack2(acc[p][nf][2], acc[p][nf][3]);
                    int byte = pos * 32 + ((8 * g) ^ (((pos >> 2) & 1) << 4));
                    *(u32x2*)(base + byte) = (u32x2){lo, hi};
                }
            } else {
                #pragma unroll
                for (int nf = 0; nf < 4; ++nf) {
                    int pos = 16 * nf + li;
                    #pragma unroll
                    for (int r = 0; r < 4; ++r) {
                        int d = 4 * g + r;
                        int byte = (pos >> 3) * 256 + d * 16 + (pos & 7) * 2;
                        *(u16*)(Vb + byte) = bfu(acc[p][nf][r]);
                    }
                }
            }
        }

        f32x4 s[4][4];
        #pragma unroll
        for (int mf = 0; mf < 4; ++mf)
            #pragma unroll
            for (int nf = 0; nf < 4; ++nf) s[mf][nf] = (f32x4){0.f,0.f,0.f,0.f};
        bf16x8 bk[4];
        #pragma unroll
        for (int nf = 0; nf < 4; ++nf) {
            int pos = 16 * nf + li;
            bk[nf] = (g < 2) ? *(const bf16x8*)(Kb + pos * 32 + ((16 * g) ^ (((pos >> 2) & 1) << 4))) : zf;
        }
        __builtin_amdgcn_s_setprio(1);
        #pragma unroll
        for (int mf = 0; mf < 4; ++mf) {
            int pos = 16 * mf + li;
            bf16x8 aq = (g < 2) ? *(const bf16x8*)(Qb + pos * 32 + ((16 * g) ^ (((pos >> 2) & 1) << 4))) : zf;
            #pragma unroll
            for (int nf = 0; nf < 4; ++nf)
                s[mf][nf] = __builtin_amdgcn_mfma_f32_16x16x32_bf16(aq, bk[nf], s[mf][nf], 0, 0, 0);
        }
        __builtin_amdgcn_s_setprio(0);

        f32x4 e[4][4];
        f32x4 rs[4];
        #pragma unroll
        for (int mf = 0; mf < 4; ++mf) rs[mf] = (f32x4){0.f,0.f,0.f,0.f};
        #pragma unroll
        for (int mf = 0; mf < 4; ++mf)
            #pragma unroll
            for (int nf = 0; nf < 4; ++nf) {
                f32x4 b4 = *(const f32x4*)(BIASF + (((head * 4 + mf) * 4 + nf) * 64 + lane) * 4);
                #pragma unroll
                for (int r = 0; r < 4; ++r) {
                    float ev = __expf(s[mf][nf][r] * 0.25f + b4[r]);
                    e[mf][nf][r] = ev;
                    rs[mf][r] += ev;
                }
            }
        #pragma unroll
        for (int mf = 0; mf < 4; ++mf)
            #pragma unroll
            for (int r = 0; r < 4; ++r) {
                float t = rs[mf][r];
                t += __shfl_xor(t, 1); t += __shfl_xor(t, 2);
                t += __shfl_xor(t, 4); t += __shfl_xor(t, 8);
                rs[mf][r] = t;
            }

        f32x4 o[4];
        #pragma unroll
        for (int mf = 0; mf < 4; ++mf) o[mf] = (f32x4){0.f,0.f,0.f,0.f};
        const bool even = !(lane & 1);
        #pragma unroll
        for (int hf = 0; hf < 2; ++hf) {
            #pragma unroll
            for (int mf = 0; mf < 4; ++mf)
                #pragma unroll
                for (int nfl = 0; nfl < 2; ++nfl) {
                    f32x4 ee = e[mf][2 * hf + nfl];
                    float p0 = __shfl_xor(ee[0], 1), p1 = __shfl_xor(ee[1], 1);
                    float p2 = __shfl_xor(ee[2], 1), p3 = __shfl_xor(ee[3], 1);
                    int jl = 16 * nfl + (li & ~1);
                    u32 w0, w1; int r0;
                    if (even) { w0 = pack2(ee[0], p0); w1 = pack2(ee[1], p1); r0 = 0; }
                    else      { w0 = pack2(p2, ee[2]); w1 = pack2(p3, ee[3]); r0 = 2; }
                    int i0 = 16 * mf + 4 * g + r0, i1 = i0 + 1;
                    *(u32*)(Pb + i0 * 64 + ((2 * jl) ^ ((i0 & 3) << 4))) = w0;
                    *(u32*)(Pb + i1 * 64 + ((2 * jl) ^ ((i1 & 3) << 4))) = w1;
                }
            bf16x8 bv = *(const bf16x8*)(Vb + (4 * hf + g) * 256 + li * 16);
            __builtin_amdgcn_s_setprio(1);
            #pragma unroll
            for (int mf = 0; mf < 4; ++mf) {
                int i = 16 * mf + li;
                bf16x8 ap = *(const bf16x8*)(Pb + i * 64 + ((16 * g) ^ ((i & 3) << 4)));
                o[mf] = __builtin_amdgcn_mfma_f32_16x16x32_bf16(ap, bv, o[mf], 0, 0, 0);
            }
            __builtin_amdgcn_s_setprio(0);
        }

        #pragma unroll
        for (int mf = 0; mf < 4; ++mf) {
            int h = wy * 8 + 2 * mf + (g >> 1);
            int wbase = wx * 8 + 4 * (g & 1);
            if (h < HC && wbase < WC) {
                float v0 = o[mf][0] / rs[mf][0], v1 = o[mf][1] / rs[mf][1];
                float v2 = o[mf][2] / rs[mf][2], v3 = o[mf][3] / rs[mf][3];
                size_t idx = ((size_t)(b * 256 + head * 16 + li) * HC + h) * XP_W + wbase + 4;
                *(u32x2*)(xp + idx) = (u32x2){pack2(v0, v1), pack2(v2, v3)};
            }
        }
    }
}

// ---------------- weight prep: WT (pre-swizzled), WP (pre-swizzled), ZP, WQ, BIASF
__global__ __launch_bounds__(256) void wprep_kernel(
    const float* __restrict__ wh, const float* __restrict__ wv,
    const float* __restrict__ wpw, const float* __restrict__ wqkv,
    const float* __restrict__ btab, u16* __restrict__ wsu)
{
    int i = blockIdx.x * 256 + threadIdx.x;
    u16* WT = wsu + WT_OFF / 2;
    u16* WP = wsu + WPW_OFF / 2;
    u16* ZP = wsu + ZP_OFF / 2;
    u16* WQp = wsu + WQ_OFF / 2;
    float* BF = (float*)(wsu + BIAS_OFF / 2);
    if (i < WT_ELEMS) {
        // WT[s][l][8]: LDS chunk l holds weight chunk c = l ^ ((l>>8&3)<<1)
        // (involution; reads use As[kb*256 + (co ^ (kb<<1))])
        int j = i & 7, l = (i >> 3) & 1023, s = i >> 13;
        int kb = (l >> 8) & 3;
        int co = (l & 255) ^ (kb << 1);
        float v = (s < 64) ? wh[co * 2048 + s * 32 + kb * 8 + j]
                           : wv[co * 2048 + (s - 64) * 32 + kb * 8 + j];
        WT[i] = bfu(v);
    } else if (i < WT_ELEMS + WPW_ELEMS) {
        int i2 = i - WT_ELEMS;
        int j = i2 & 7, l = (i2 >> 3) & 1023, s = i2 >> 13;
        int kb = (l >> 8) & 3;
        int co = (l & 255) ^ (kb << 1);
        WP[i2] = bfu(wpw[co * 256 + s * 32 + kb * 8 + j]);
    } else if (i < WT_ELEMS + WPW_ELEMS + (int)(ZP_BYTES / 2)) {
        ZP[i - WT_ELEMS - WPW_ELEMS] = 0;
    } else if (i < WT_ELEMS + WPW_ELEMS + (int)(ZP_BYTES / 2) + WQ_ELEMS) {
        int i4 = i - WT_ELEMS - WPW_ELEMS - (int)(ZP_BYTES / 2);
        WQp[i4] = bfu(wqkv[i4]);
    } else {
        int i5 = i - WT_ELEMS - WPW_ELEMS - (int)(ZP_BYTES / 2) - WQ_ELEMS;
        if (i5 < 16384) {
            int lane = i5 & 63, nf = (i5 >> 6) & 3, mf = (i5 >> 8) & 3, head = i5 >> 10;
            int gg = lane >> 4, ll = lane & 15;
            #pragma unroll
            for (int r = 0; r < 4; ++r) {
                int row = 16 * mf + 4 * gg + r;
                int col = 16 * nf + ll;
                int dy = (row >> 3) - (col >> 3) + 7;
                int dx = (row & 7) - (col & 7) + 7;
                BF[i5 * 4 + r] = btab[(dy * 15 + dx) * NHEADS + head];
            }
        }
    }
}

// ---------------- halo fill for XP: wp 0..3, 256..263 ------------------------
__global__ __launch_bounds__(256) void halo_kernel(u16* __restrict__ xp)
{
    int i = blockIdx.x * 256 + threadIdx.x;
    if (i >= 129024 * 12) return;
    int row = i / 12, c = i % 12;
    int wp = (c < 4) ? c : 252 + c;
    u16 v = 0;
    if (wp == 256) v = xp[row * XP_W + 254];
    xp[row * XP_W + wp] = v;
}

// ---------------- Kernel B: sepconv bf16 MFMA, K=4096 ------------------------
// grid 504 = (b,h), XCD-swizzled. 512 thr, 8 waves of 128co x 64w.
// R6 loop skeleton (reg-staged loads BEFORE barrier); pre-swizzled WT (linear
// LDS write addr); bf16 P output.
__global__ __launch_bounds__(512, 2) void sepconv_mfma(
    const u16* __restrict__ xp, const u16* __restrict__ WT,
    const u16* __restrict__ ZP,
    const float* __restrict__ b_h, const float* __restrict__ b_v,
    u16* __restrict__ P)
{
    __shared__ __align__(16) u16 As[2][8192];   // [kb][co^swz][8] via WT layout
    __shared__ __align__(16) u16 Bs[2][256 * 36];

    const int bid = blockIdx.x;                 // 504 = 8*63, bijective swizzle
    const int zz = (bid & 7) * 63 + (bid >> 3);
    const int h = zz % HC, b = zz / HC;
    const int tid = threadIdx.x;
    const int lane = tid & 63, wid = tid >> 6;
    const int wr = wid >> 2, wc = wid & 3;
    const int cq = lane & 15, kb = lane >> 4;

    const int wl2 = (tid & 127) * 2;
    const int oc = tid >> 7;

    const u16* hcur[8];
    int hstep[8];
    #pragma unroll
    for (int t = 0; t < 8; ++t) {
        int j = h + t - 3;
        bool valid = (j >= 0 && j <= 252);
        int jr = (j == 252) ? 250 : j;
        hcur[t] = valid ? (xp + (size_t)b * XP_CHW + (size_t)jr * XP_W) : ZP;
        hstep[t] = valid ? 4 * XP_HW : 0;
    }
    const u16* vbase = xp + (size_t)b * XP_CHW + (size_t)h * XP_W;
    const int hvoff = oc * XP_HW + wl2 + 4;

    const int bw0 = wl2 * 36 + oc * 8;
    const int bw1 = bw0 + 36;

    f32x4 acc[8][4];
    #pragma unroll
    for (int m = 0; m < 8; ++m)
        #pragma unroll
        for (int n = 0; n < 4; ++n) acc[m][n] = (f32x4){0.f, 0.f, 0.f, 0.f};

    u32x4 rA[2];
    u32 rB[8];

    // ---- prologue: load + write step 0 (linear A write — WT pre-swizzled) ---
    rA[0] = *(const u32x4*)(WT + (size_t)tid * 8);
    rA[1] = *(const u32x4*)(WT + (size_t)(512 + tid) * 8);
    #pragma unroll
    for (int t = 0; t < 8; ++t)
        rB[t] = *(const u32*)(hcur[t] + hvoff);
    *(u32x4*)&As[0][(size_t)tid * 8] = rA[0];
    *(u32x4*)&As[0][(size_t)(512 + tid) * 8] = rA[1];
    {
        union { bf16x8 v; u32 u[4]; } p0, p1;
        #pragma unroll
        for (int q = 0; q < 4; ++q) {
            p0.u[q] = __builtin_amdgcn_perm(rB[2 * q + 1], rB[2 * q], 0x05040100u);
            p1.u[q] = __builtin_amdgcn_perm(rB[2 * q + 1], rB[2 * q], 0x07060302u);
        }
        *(bf16x8*)&Bs[0][bw0] = p0.v;
        *(bf16x8*)&Bs[0][bw1] = p1.v;
    }

    #pragma unroll 1
    for (int s = 0; s < 128; ++s) {
        const int cur = s & 1;
        const int s1 = s + 1;
        const bool hph1 = (s1 < 64);
        if (s1 < 128) {
            rA[0] = *(const u32x4*)(WT + (size_t)s1 * 8192 + (size_t)tid * 8);
            rA[1] = *(const u32x4*)(WT + (size_t)s1 * 8192 + (size_t)(512 + tid) * 8);
            if (hph1) {
                #pragma unroll
                for (int t = 0; t < 8; ++t) hcur[t] += hstep[t];
                #pragma unroll
                for (int t = 0; t < 8; ++t)
                    rB[t] = *(const u32*)(hcur[t] + hvoff);
            } else {
                int off = ((s1 - 64) * 4 + oc) * XP_HW + wl2;
                #pragma unroll
                for (int l = 0; l < 6; ++l)
                    rB[l] = *(const u32*)(vbase + off + 2 * l);
            }
        }
        __syncthreads();

        {
            bf16x8 af[8], bfr[4];
            #pragma unroll
            for (int m = 0; m < 8; ++m) {
                int row = wr * 128 + m * 16 + cq;
                af[m] = *(const bf16x8*)&As[cur][(kb * 256 + (row ^ (kb << 1))) * 8];
            }
            #pragma unroll
            for (int n = 0; n < 4; ++n)
                bfr[n] = *(const bf16x8*)&Bs[cur][(wc * 64 + n * 16 + cq) * 36 + kb * 8];
            __builtin_amdgcn_s_setprio(1);
            #pragma unroll
            for (int m = 0; m < 8; ++m)
                #pragma unroll
                for (int n = 0; n < 4; ++n)
                    acc[m][n] = __builtin_amdgcn_mfma_f32_16x16x32_bf16(af[m], bfr[n], acc[m][n], 0, 0, 0);
            __builtin_amdgcn_s_setprio(0);
        }

        if (s1 < 128) {
            const int nxt = cur ^ 1;
            *(u32x4*)&As[nxt][(size_t)tid * 8] = rA[0];
            *(u32x4*)&As[nxt][(size_t)(512 + tid) * 8] = rA[1];
            union { bf16x8 v; u32 u[4]; } p0, p1;
            if (hph1) {
                #pragma unroll
                for (int q = 0; q < 4; ++q) {
                    p0.u[q] = __builtin_amdgcn_perm(rB[2 * q + 1], rB[2 * q], 0x05040100u);
                    p1.u[q] = __builtin_amdgcn_perm(rB[2 * q + 1], rB[2 * q], 0x07060302u);
                }
            } else {
                #pragma unroll
                for (int q = 0; q < 4; ++q)
                    p0.u[q] = __builtin_amdgcn_alignbit(rB[q + 1], rB[q], 16);
                p1.u[0] = rB[1]; p1.u[1] = rB[2];
                p1.u[2] = rB[3]; p1.u[3] = rB[4];
            }
            *(bf16x8*)&Bs[nxt][bw0] = p0.v;
            *(bf16x8*)&Bs[nxt][bw1] = p1.v;
        }
    }

    // ---- epilogue: bias + bf16 store ----
    const int rq = lane >> 4, cc = lane & 15;
    #pragma unroll
    for (int m = 0; m < 8; ++m) {
        int cgb = wr * 128 + m * 16 + rq * 4;
        float bias[4];
        #pragma unroll
        for (int rr = 0; rr < 4; ++rr) bias[rr] = b_h[cgb + rr] + b_v[cgb + rr];
        #pragma unroll
        for (int n = 0; n < 4; ++n) {
            int wg = wc * 64 + n * 16 + cc;
            if (wg < WC) {
                #pragma unroll
                for (int rr = 0; rr < 4; ++rr)
                    P[((size_t)(b * CD + cgb + rr) * HC + h) * WC + wg] = bfu(acc[m][n][rr] + bias[rr]);
            }
        }
    }
}

// ---------------- Kernel C: depthwise 8x8 conv + BN (bf16 in) -> bf16 Y ------
__global__ __launch_bounds__(256) void dwbn_kernel(
    const u16* __restrict__ P, const float* __restrict__ w_dw,
    const float* __restrict__ gamma, const float* __restrict__ beta,
    const float* __restrict__ mean, const float* __restrict__ var,
    __hip_bfloat16* __restrict__ Yb)
{
    __shared__ float ps[15][42];
    __shared__ float wd[64];
    const int bw = blockIdx.x, bh = blockIdx.y, bz = blockIdx.z;
    const int b = bz >> 8, c = bz & 255;
    const int h0 = bh * 8, w0 = bw * 32;
    const int tid = threadIdx.x;
    if (tid < 64) wd[tid] = w_dw[c * 64 + tid];
    for (int it = 0; it < 3; ++it) {
        int flat = tid + it * 256;
        if (flat < 630) {
            int row = flat / 42, col = flat % 42;
            int j = h0 - 3 + row, wcol = w0 - 3 + col;
            float v = 0.f;
            if (j >= 0 && j <= HC && wcol >= 0 && wcol <= WC) {
                int jr = (j == HC) ? (HC - 2) : j;
                int wr2 = (wcol == WC) ? (WC - 2) : wcol;
                v = bf2f(P[((size_t)(b * CD + c) * HC + jr) * WC + wr2]);
            }
            ps[row][col] = v;
        }
    }
    __syncthreads();
    const int r = tid >> 5, cc = tid & 31;
    const int h = h0 + r, w = w0 + cc;
    if (h < HC && w < WC) {
        float s = 0.f;
        #pragma unroll
        for (int u = 0; u < 8; ++u)
            #pragma unroll
            for (int v2 = 0; v2 < 8; ++v2)
                s += wd[u * 8 + v2] * ps[r + u][cc + v2];
        const float inv = gamma[c] * rsqrtf(var[c] + 1e-5f);
        Yb[((b * CD + c) * HC + h) * WC + w] = __float2bfloat16(s * inv + (beta[c] - mean[c] * inv));
    }
}

// ---------------- Kernel D: pointwise 1x1, bf16 MFMA, K=256 ------------------
// grid 504 = (b,h), XCD-swizzled. 512 thr, 8 waves of 128co x 64w. R6 skeleton.
__global__ __launch_bounds__(512, 2) void pw_mfma(
    const u16* __restrict__ Y, const u16* __restrict__ WP,
    float* __restrict__ O)
{
    __shared__ __align__(16) u16 As[2][8192];
    __shared__ __align__(16) u16 Bs[2][256 * 36];

    const int bid = blockIdx.x;
    const int zz = (bid & 7) * 63 + (bid >> 3);
    const int h = zz % HC, b = zz / HC;
    const int tid = threadIdx.x;
    const int lane = tid & 63, wid = tid >> 6;
    const int wr = wid >> 2, wc = wid & 3;
    const int cq = lane & 15, kb = lane >> 4;

    const int wl2 = (tid & 127) * 2;
    const int oc = tid >> 7;

    const u16* yb = Y + ((size_t)(b * 256 + oc * 8) * HC + h) * WC + wl2;

    const int bw0 = wl2 * 36 + oc * 8;
    const int bw1 = bw0 + 36;

    f32x4 acc[8][4];
    #pragma unroll
    for (int m = 0; m < 8; ++m)
        #pragma unroll
        for (int n = 0; n < 4; ++n) acc[m][n] = (f32x4){0.f, 0.f, 0.f, 0.f};

    u32x4 rA[2];
    u32 rB[8];

    // ---- prologue ----
    rA[0] = *(const u32x4*)(WP + (size_t)tid * 8);
    rA[1] = *(const u32x4*)(WP + (size_t)(512 + tid) * 8);
    #pragma unroll
    for (int j = 0; j < 8; ++j)
        rB[j] = *(const u32*)(yb + (size_t)j * (HC * WC));
    *(u32x4*)&As[0][(size_t)tid * 8] = rA[0];
    *(u32x4*)&As[0][(size_t)(512 + tid) * 8] = rA[1];
    {
        union { bf16x8 v; u32 u[4]; } p0, p1;
        #pragma unroll
        for (int q = 0; q < 4; ++q) {
            p0.u[q] = __builtin_amdgcn_perm(rB[2 * q + 1], rB[2 * q], 0x05040100u);
            p1.u[q] = __builtin_amdgcn_perm(rB[2 * q + 1], rB[2 * q], 0x07060302u);
        }
        *(bf16x8*)&Bs[0][bw0] = p0.v;
        *(bf16x8*)&Bs[0][bw1] = p1.v;
    }

    #pragma unroll 1
    for (int s = 0; s < 8; ++s) {
        const int cur = s & 1;
        const int s1 = s + 1;
        if (s1 < 8) {
            rA[0] = *(const u32x4*)(WP + (size_t)s1 * 8192 + (size_t)tid * 8);
            rA[1] = *(const u32x4*)(WP + (size_t)s1 * 8192 + (size_t)(512 + tid) * 8);
            #pragma unroll
            for (int j = 0; j < 8; ++j)
                rB[j] = *(const u32*)(yb + (size_t)(s1 * 32 + j) * (HC * WC));
        }
        __syncthreads();

        {
            bf16x8 af[8], bfr[4];
            #pragma unroll
            for (int m = 0; m < 8; ++m) {
                int row = wr * 128 + m * 16 + cq;
                af[m] = *(const bf16x8*)&As[cur][(kb * 256 + (row ^ (kb << 1))) * 8];
            }
            #pragma unroll
            for (int n = 0; n < 4; ++n)
                bfr[n] = *(const bf16x8*)&Bs[cur][(wc * 64 + n * 16 + cq) * 36 + kb * 8];
            __builtin_amdgcn_s_setprio(1);
            #pragma unroll
            for (int m = 0; m < 8; ++m)
                #pragma unroll
                for (int n = 0; n < 4; ++n)
                    acc[m][n] = __builtin_amdgcn_mfma_f32_16x16x32_bf16(af[m], bfr[n], acc[m][n], 0, 0, 0);
            __builtin_amdgcn_s_setprio(0);
        }

        if (s1 < 8) {
            const int nxt = cur ^ 1;
            *(u32x4*)&As[nxt][(size_t)tid * 8] = rA[0];
            *(u32x4*)&As[nxt][(size_t)(512 + tid) * 8] = rA[1];
            union { bf16x8 v; u32 u[4]; } p0, p1;
            #pragma unroll
            for (int q = 0; q < 4; ++q) {
                p0.u[q] = __builtin_amdgcn_perm(rB[2 * q + 1], rB[2 * q], 0x05040100u);
                p1.u[q] = __builtin_amdgcn_perm(rB[2 * q + 1], rB[2 * q], 0x07060302u);
            }
            *(bf16x8*)&Bs[nxt][bw0] = p0.v;
            *(bf16x8*)&Bs[nxt][bw1] = p1.v;
        }
    }

    const int rq = lane >> 4, cc = lane & 15;
    #pragma unroll
    for (int m = 0; m < 8; ++m) {
        int cgb = wr * 128 + m * 16 + rq * 4;
        #pragma unroll
        for (int n = 0; n < 4; ++n) {
            int wg = wc * 64 + n * 16 + cc;
            if (wg < WC) {
                #pragma unroll
                for (int rr = 0; rr < 4; ++rr)
                    O[((size_t)(b * CD + cgb + rr) * HC + h) * WC + wg] = acc[m][n][rr];
            }
        }
    }
}

extern "C" void kernel_launch(void* const* d_in, const int* in_sizes, int n_in,
                              void* d_out, int out_size, void* d_ws, size_t ws_size,
                              hipStream_t stream)
{
    const float* x      = (const float*)d_in[0];
    const float* w_qkv  = (const float*)d_in[1];
    const float* bias_t = (const float*)d_in[2];
    const float* w_h    = (const float*)d_in[3];
    const float* b_h    = (const float*)d_in[4];
    const float* w_v    = (const float*)d_in[5];
    const float* b_v    = (const float*)d_in[6];
    const float* w_dw   = (const float*)d_in[7];
    const float* bn_g   = (const float*)d_in[8];
    const float* bn_b   = (const float*)d_in[9];
    const float* bn_m   = (const float*)d_in[10];
    const float* bn_v   = (const float*)d_in[11];
    const float* w_pw   = (const float*)d_in[12];
    float* out = (float*)d_out;

    u16* wsu = (u16*)d_ws;
    const u16* XPu = wsu;
    const u16* ZPu = wsu + ZP_OFF / 2;
    const u16* WTu = wsu + WT_OFF / 2;
    const u16* WPu = wsu + WPW_OFF / 2;
    const u16* WQu = wsu + WQ_OFF / 2;
    const float* BFu = (const float*)(wsu + BIAS_OFF / 2);

    // wprep -> attn(MFMA) -> halo -> sepconv(MFMA, bf16 P) -> dwbn -> pw(MFMA)
    wprep_kernel<<<5984, 256, 0, stream>>>(w_h, w_v, w_pw, w_qkv, bias_t, wsu);
    attn_mfma<<<2048, 256, 0, stream>>>(x, WQu, BFu, wsu);
    halo_kernel<<<6048, 256, 0, stream>>>(wsu);
    sepconv_mfma<<<504, 512, 0, stream>>>(XPu, WTu, ZPu, b_h, b_v, (u16*)d_out);
    dwbn_kernel<<<dim3(8, 32, 512), 256, 0, stream>>>((const u16*)d_out, w_dw, bn_g, bn_b,
                                                      bn_m, bn_v, (__hip_bfloat16*)d_ws);
    pw_mfma<<<504, 512, 0, stream>>>(wsu, WPu, out);
}